// Round 5
// baseline (796.273 us; speedup 1.0000x reference)
//
#include <hip/hip_runtime.h>

// ============================================================================
// GNN_22170621182157 R5: stream-K (512 uniform blocks) for the i8 logit GEMMs
// to remove wave-quantization idle (adj 18.6%, S 25%, Mt 50%).
//   - Mt/S (digit output): boundary-tile partials (fp32 comb) -> head/tail
//     slots in the dead adj buffer; fixup kernel sums + requantizes.
//   - adj (fp32 output): split tiles pre-zeroed, partial segments atomicAdd.
// K-unit quotas divide exactly: Mt 8192/512=16, S 36864/512=72, adj 41472/512=81.
//
// Math (softmax row-shift invariance):
//   softmax(adj) == softmax( S F^T + 1*c^T ), S = F Mt^T, Mt = Wk Wq^T,
//   c = F (Wk bq);  out = P (F Wu) + bu.
// Fixed-point: x ~ r/s, r = a1*256 + a0 (i8 digits). s_F=s_S=5440,
// s_W=s_Mt=261120. comb = 65536*hh + 256*(a1b0+a0b1) + a0b0 (i32 exact).
// ============================================================================

typedef unsigned short u16;
typedef unsigned int   u32;
typedef signed char    i8;
typedef _Float16 f16;
typedef f16    f16x8 __attribute__((ext_vector_type(8)));
typedef float  f32x4 __attribute__((ext_vector_type(4)));
typedef int    i32x4 __attribute__((ext_vector_type(4)));
typedef u32    u32x4 __attribute__((ext_vector_type(4)));
typedef u16    u16x4 __attribute__((ext_vector_type(4)));

#define WAIT_VM8   0x0F78  // vmcnt(8),  exp 7, lgkm 15
#define WAIT_VM4   0x0F74  // vmcnt(4)
#define WAIT_VM0   0x0F70  // vmcnt(0)
#define WAIT_LGKM0 0xC07F  // lgkmcnt(0), vm 63, exp 7

__device__ __forceinline__ void gload16(const void* g, void* l) {
    __builtin_amdgcn_global_load_lds(
        (const __attribute__((address_space(1))) unsigned int*)g,
        (__attribute__((address_space(3))) unsigned int*)l, 16, 0, 0);
}

__device__ __forceinline__ void digits256(float v, float s, i8& d1, i8& d0) {
    float f = fminf(fmaxf(v * s, -32600.0f), 32600.0f);
    int r = __float2int_rn(f);
    int a1 = (r + 128) >> 8;
    int a0 = r - (a1 << 8);
    d1 = (i8)a1;
    d0 = (i8)a0;
}

// column-panel tile order within batch z (adjacent tiles share B panel)
__device__ __forceinline__ void tile_decomp(int t, int ntM, int ntN,
                                            int& z, int& ty, int& tx) {
    const int per = ntM * ntN;
    z = t / per;
    const int q = t - z * per;
    tx = q / ntM;
    ty = q - tx * ntM;
}

// ---------------------------------------------------------------------------
// Pre-passes
// ---------------------------------------------------------------------------
__global__ __launch_bounds__(256) void quantFc_k(const float* __restrict__ F,
                                                 const float* __restrict__ u,
                                                 u16* __restrict__ F16,
                                                 i8* __restrict__ hi,
                                                 i8* __restrict__ lo,
                                                 float* __restrict__ c) {
    const long row = blockIdx.x;
    const int tid = threadIdx.x;
    const float* fr = F + row * 2048;
    float dot = 0.f;
    #pragma unroll
    for (int t = 0; t < 8; ++t) {
        const int i = t * 256 + tid;
        const float v = fr[i];
        F16[row * 2048 + i] = __builtin_bit_cast(u16, (f16)v);
        i8 d1, d0;
        digits256(v, 5440.0f, d1, d0);
        hi[row * 2048 + i] = d1;
        lo[row * 2048 + i] = d0;
        dot += v * u[i];
    }
    #pragma unroll
    for (int off = 32; off >= 1; off >>= 1) dot += __shfl_down(dot, off);
    __shared__ float red[4];
    if ((tid & 63) == 0) red[tid >> 6] = dot;
    __syncthreads();
    if (tid == 0) c[row] = red[0] + red[1] + red[2] + red[3];
}

__global__ __launch_bounds__(256) void quantW_k(const float* __restrict__ x,
                                                i8* __restrict__ hi,
                                                i8* __restrict__ lo, long n) {
    long i = (long)blockIdx.x * 256 + threadIdx.x;
    if (i < n) {
        i8 d1, d0;
        digits256(x[i], 261120.0f, d1, d0);
        hi[i] = d1;
        lo[i] = d0;
    }
}

__global__ __launch_bounds__(256) void wut_k(const float* __restrict__ Wu,
                                             u16* __restrict__ WuT) {
    __shared__ float t[32][33];
    const int bx = blockIdx.x * 32;
    const int by = blockIdx.y * 32;
    const int lx = threadIdx.x, ly = threadIdx.y;
    #pragma unroll
    for (int dy = 0; dy < 32; dy += 8)
        t[ly + dy][lx] = Wu[(long)(by + ly + dy) * 1024 + bx + lx];
    __syncthreads();
    #pragma unroll
    for (int dy = 0; dy < 32; dy += 8)
        WuT[(long)(bx + ly + dy) * 2048 + by + lx] =
            __builtin_bit_cast(u16, (f16)t[lx][ly + dy]);
}

__global__ __launch_bounds__(256) void gemv_k(const float* __restrict__ A,
                                              const float* __restrict__ x,
                                              float* __restrict__ y, int ncols) {
    const long row = blockIdx.x;
    const float* ar = A + row * (long)ncols;
    float s = 0.f;
    for (int i = threadIdx.x; i < ncols; i += 256) s += ar[i] * x[i];
    #pragma unroll
    for (int off = 32; off >= 1; off >>= 1) s += __shfl_down(s, off);
    __shared__ float red[4];
    if ((threadIdx.x & 63) == 0) red[threadIdx.x >> 6] = s;
    __syncthreads();
    if (threadIdx.x == 0) y[row] = red[0] + red[1] + red[2] + red[3];
}

// ---------------------------------------------------------------------------
// Stream-K i8 2-digit 4-term GEMM.  512 blocks, per-block quota upb K-units
// (1 unit = BK=64 of one tile).  EPI 0: digit out (partial -> slots);
// EPI 1: fp32 out (partial -> atomicAdd; split tiles pre-zeroed).
// ---------------------------------------------------------------------------
template <int EPI>
__global__ __launch_bounds__(256, 2) void gemm_i8_sk(
    const i8* __restrict__ Ah, const i8* __restrict__ Al,
    const i8* __restrict__ Bh, const i8* __restrict__ Bl,
    i8* __restrict__ Qh, i8* __restrict__ Ql, float* __restrict__ Cf,
    float* __restrict__ phead, float* __restrict__ ptail,
    float oscale, int N, int K, long strA, long strB, long strC,
    int ntM, int ntN, int nk, int upb) {
    __shared__ __align__(16) i8 lds[2][32768];

    const int tid  = threadIdx.x;
    const int lane = tid & 63;
    const int wv   = tid >> 6;
    const int wm   = wv >> 1, wn = wv & 1;
    const int l16  = lane & 15, kq = lane >> 4;
    const int blk  = blockIdx.x;

    const int l4r = lane >> 2, l4c = lane & 3;
    int rin[2], kqw[2], ldsoff[2];
    #pragma unroll
    for (int h = 0; h < 2; ++h) {
        rin[h] = h * 64 + wv * 16 + l4r;
        kqw[h] = (l4c - (rin[h] >> 1)) & 3;
        ldsoff[h] = (h * 64 + wv * 16) * 64;
    }
    int aoff[4], boff[4];
    #pragma unroll
    for (int i = 0; i < 4; ++i) {
        const int rA = wm * 64 + i * 16 + l16;
        aoff[i] = rA * 64 + ((kq + (rA >> 1)) & 3) * 16;
        const int rB = wn * 64 + i * 16 + l16;
        boff[i] = rB * 64 + ((kq + (rB >> 1)) & 3) * 16;
    }

    const i32x4 izero = {0, 0, 0, 0};
    long ku = (long)blk * upb;
    const long ku1 = ku + upb;
    bool firstSeg = true;

    while (ku < ku1) {
        const int t  = (int)(ku / nk);
        const int ks = (int)(ku - (long)t * nk);
        const int ke = (int)min((long)nk, ks + (ku1 - ku));
        int z, ty, tx;
        tile_decomp(t, ntM, ntN, z, ty, tx);
        const long rowBase = (long)ty * 128;
        const long colBase = (long)tx * 128;

        const i8* pAh = Ah + (long)z * strA;
        const i8* pAl = Al + (long)z * strA;
        const i8* pBh = Bh + (long)z * strB;
        const i8* pBl = Bl + (long)z * strB;

        u32 voffA[2], voffB[2];
        #pragma unroll
        for (int h = 0; h < 2; ++h) {
            voffA[h] = (u32)((rowBase + rin[h]) * (long)K) + kqw[h] * 16 + ks * 64;
            voffB[h] = (u32)((colBase + rin[h]) * (long)K) + kqw[h] * 16 + ks * 64;
        }

        i32x4 ahh[4][4], acx[4][4], all_[4][4];
        #pragma unroll
        for (int i = 0; i < 4; ++i)
            #pragma unroll
            for (int j = 0; j < 4; ++j) { ahh[i][j] = izero; acx[i][j] = izero; all_[i][j] = izero; }

        // prologue DMA -> buf 0
        #pragma unroll
        for (int h = 0; h < 2; ++h) {
            gload16(pAh + voffA[h], &lds[0][0]     + ldsoff[h]);
            gload16(pAl + voffA[h], &lds[0][8192]  + ldsoff[h]);
            gload16(pBh + voffB[h], &lds[0][16384] + ldsoff[h]);
            gload16(pBl + voffB[h], &lds[0][24576] + ldsoff[h]);
        }

        for (int kt = ks; kt < ke; ++kt) {
            const int cur = (kt - ks) & 1;
            if (kt + 1 < ke) {
                const long ko = (long)(kt + 1 - ks) * 64;
                i8* nb = lds[1 - cur];
                #pragma unroll
                for (int h = 0; h < 2; ++h) {
                    gload16(pAh + voffA[h] + ko, nb         + ldsoff[h]);
                    gload16(pAl + voffA[h] + ko, nb + 8192  + ldsoff[h]);
                    gload16(pBh + voffB[h] + ko, nb + 16384 + ldsoff[h]);
                    gload16(pBl + voffB[h] + ko, nb + 24576 + ldsoff[h]);
                }
                __builtin_amdgcn_s_waitcnt(WAIT_VM8);
            } else {
                __builtin_amdgcn_s_waitcnt(WAIT_VM0);
            }
            __builtin_amdgcn_s_barrier();

            const i8* base = lds[cur];
            i32x4 fbh[4], fbl[4];
            #pragma unroll
            for (int j = 0; j < 4; ++j) {
                fbh[j] = *(const i32x4*)(base + 16384 + boff[j]);
                fbl[j] = *(const i32x4*)(base + 24576 + boff[j]);
            }
            #pragma unroll
            for (int i = 0; i < 4; ++i) {
                i32x4 fah = *(const i32x4*)(base + aoff[i]);
                i32x4 fal = *(const i32x4*)(base + 8192 + aoff[i]);
                #pragma unroll
                for (int j = 0; j < 4; ++j) {
                    ahh[i][j]  = __builtin_amdgcn_mfma_i32_16x16x64_i8(fah, fbh[j], ahh[i][j], 0, 0, 0);
                    acx[i][j]  = __builtin_amdgcn_mfma_i32_16x16x64_i8(fah, fbl[j], acx[i][j], 0, 0, 0);
                    all_[i][j] = __builtin_amdgcn_mfma_i32_16x16x64_i8(fal, fbl[j], all_[i][j], 0, 0, 0);
                    acx[i][j]  = __builtin_amdgcn_mfma_i32_16x16x64_i8(fal, fbh[j], acx[i][j], 0, 0, 0);
                }
            }
            __builtin_amdgcn_s_waitcnt(WAIT_LGKM0);
            __builtin_amdgcn_s_barrier();
        }

        // epilogue for this segment
        const bool full = (ks == 0) && (ke == nk);
        float* ps = (firstSeg ? phead : ptail) + (long)blk * 16384;
        #pragma unroll
        for (int i = 0; i < 4; ++i) {
            const int lr0 = wm * 64 + i * 16 + kq * 4;
            const long gr0 = rowBase + lr0;
            #pragma unroll
            for (int j = 0; j < 4; ++j) {
                const int lc = wn * 64 + j * 16 + l16;
                const long gc = colBase + lc;
                #pragma unroll
                for (int r = 0; r < 4; ++r) {
                    const float comb = 65536.0f * (float)ahh[i][j][r] +
                                         256.0f * (float)acx[i][j][r] +
                                                 (float)all_[i][j][r];
                    if constexpr (EPI == 0) {
                        if (full) {
                            const long o = (gr0 + r) * (long)N + gc;
                            i8 d1, d0;
                            digits256(comb, oscale, d1, d0);
                            Qh[o] = d1;
                            Ql[o] = d0;
                        } else {
                            ps[(lr0 + r) * 128 + lc] = comb;
                        }
                    } else {
                        float* C = Cf + (long)z * strC;
                        const long o = (gr0 + r) * (long)N + gc;
                        if (full) C[o] = comb * oscale;
                        else atomicAdd(&C[o], comb * oscale);
                    }
                }
            }
        }
        firstSeg = false;
        ku += (ke - ks);
    }
}

// ---------------------------------------------------------------------------
// Fixup for digit-output stream-K: per split tile, sum partials + requantize.
// ---------------------------------------------------------------------------
__global__ __launch_bounds__(256) void fixup_k(
    const float* __restrict__ phead, const float* __restrict__ ptail,
    i8* __restrict__ Qh, i8* __restrict__ Ql, float oscale,
    int ntM, int ntN, int nk, int upb, int N) {
    const int t = blockIdx.x;
    const int b_lo = (t * nk) / upb;
    const int b_hi = ((t + 1) * nk - 1) / upb;
    if (b_lo == b_hi) return;  // tile was whole
    int z, ty, tx;
    tile_decomp(t, ntM, ntN, z, ty, tx);
    const long rowBase = (long)ty * 128;
    const long colBase = (long)tx * 128;
    const int tid = threadIdx.x;
    #pragma unroll
    for (int k = 0; k < 64; ++k) {
        const int e = k * 256 + tid;
        float s = 0.f;
        for (int b = b_lo; b <= b_hi; ++b) {
            const float* ps = (((long)b * upb >= (long)t * nk) ? phead : ptail)
                              + (long)b * 16384;
            s += ps[e];
        }
        const int lr = e >> 7, lc = e & 127;
        i8 d1, d0;
        digits256(s, oscale, d1, d0);
        const long o = (rowBase + lr) * (long)N + colBase + lc;
        Qh[o] = d1;
        Ql[o] = d0;
    }
}

// Zero the split tiles of a fp32 stream-K output (before atomicAdd pass).
__global__ __launch_bounds__(256) void zero_split_k(
    float* __restrict__ Cf, int ntM, int ntN, int nk, int upb, int N, long strC) {
    const int t = blockIdx.x;
    const int b_lo = (t * nk) / upb;
    const int b_hi = ((t + 1) * nk - 1) / upb;
    if (b_lo == b_hi) return;
    int z, ty, tx;
    tile_decomp(t, ntM, ntN, z, ty, tx);
    float* C = Cf + (long)z * strC;
    const long rowBase = (long)ty * 128;
    const long colBase = (long)tx * 128;
    const int tid = threadIdx.x;
    #pragma unroll
    for (int k = 0; k < 64; ++k) {
        const int e = k * 256 + tid;
        C[(rowBase + (e >> 7)) * (long)N + colBase + (e & 127)] = 0.f;
    }
}

// ---------------------------------------------------------------------------
// fp16 GEMM (unchanged from R4): gload+dbuf+raw barriers.
// EPI 2: fp16 transposed write (vT); EPI 3: fp32 + bias[col].
// ---------------------------------------------------------------------------
__device__ __forceinline__ void tile_swizzle(int& tx, int& ty) {
    const int gx = gridDim.x, gy = gridDim.y;
    const int lin = blockIdx.y * gx + blockIdx.x;
    const int G = 4;
    const int gid = lin / (G * gx);
    const int g0 = gid * G;
    const int gh = min(G, gy - g0);
    const int rem = lin - gid * (G * gx);
    ty = g0 + rem % gh;
    tx = rem / gh;
}

template <int EPI>
__global__ __launch_bounds__(256, 3) void gemm_f16(
    const u16* __restrict__ A, const u16* __restrict__ B,
    u16* __restrict__ Ch, float* __restrict__ Cf,
    const float* __restrict__ bias,
    int N, int K, long strA, long strB, long strC) {
    __shared__ __align__(16) i8 lds[2][16384];

    const int tid  = threadIdx.x;
    const int lane = tid & 63;
    const int wv   = tid >> 6;
    const int wm   = wv >> 1, wn = wv & 1;
    const int l16  = lane & 15, kq = lane >> 4;
    const int z    = blockIdx.z;
    int tx, ty;
    tile_swizzle(tx, ty);
    const long rowBase = (long)ty * 128;
    const long colBase = (long)tx * 128;

    const u16* pA = A + (long)z * strA;
    const u16* pB = B + (long)z * strB;

    const int l4r = lane >> 2, l4c = lane & 3;
    u32 voffA[2], voffB[2];
    int ldsoff[2];
    #pragma unroll
    for (int h = 0; h < 2; ++h) {
        const int rin = h * 64 + wv * 16 + l4r;
        const int kw = (l4c - (rin >> 1)) & 3;
        voffA[h] = (u32)((rowBase + rin) * (long)K) + kw * 8;
        voffB[h] = (u32)((colBase + rin) * (long)K) + kw * 8;
        ldsoff[h] = (h * 64 + wv * 16) * 64;
    }
    int aoff[4], boff[4];
    #pragma unroll
    for (int i = 0; i < 4; ++i) {
        const int rA = wm * 64 + i * 16 + l16;
        aoff[i] = rA * 64 + ((kq + (rA >> 1)) & 3) * 16;
        const int rB = wn * 64 + i * 16 + l16;
        boff[i] = rB * 64 + ((kq + (rB >> 1)) & 3) * 16;
    }

    const f32x4 vzero = {0.f, 0.f, 0.f, 0.f};
    f32x4 acc[4][4];
    #pragma unroll
    for (int i = 0; i < 4; ++i)
        #pragma unroll
        for (int j = 0; j < 4; ++j) acc[i][j] = vzero;

    const int nk = K >> 5;

    #pragma unroll
    for (int h = 0; h < 2; ++h) {
        gload16(pA + voffA[h], &lds[0][0]    + ldsoff[h]);
        gload16(pB + voffB[h], &lds[0][8192] + ldsoff[h]);
    }

    for (int kt = 0; kt < nk; ++kt) {
        const int cur = kt & 1;
        if (kt + 1 < nk) {
            const long ko = (long)(kt + 1) * 32;
            i8* nb = lds[1 - cur];
            #pragma unroll
            for (int h = 0; h < 2; ++h) {
                gload16(pA + voffA[h] + ko, nb        + ldsoff[h]);
                gload16(pB + voffB[h] + ko, nb + 8192 + ldsoff[h]);
            }
            __builtin_amdgcn_s_waitcnt(WAIT_VM4);
        } else {
            __builtin_amdgcn_s_waitcnt(WAIT_VM0);
        }
        __builtin_amdgcn_s_barrier();

        const i8* base = lds[cur];
        f16x8 fa[4];
        #pragma unroll
        for (int i = 0; i < 4; ++i)
            fa[i] = __builtin_bit_cast(f16x8, *(const u32x4*)(base + aoff[i]));
        #pragma unroll
        for (int j = 0; j < 4; ++j) {
            f16x8 fb = __builtin_bit_cast(f16x8, *(const u32x4*)(base + 8192 + boff[j]));
            #pragma unroll
            for (int i = 0; i < 4; ++i)
                acc[i][j] = __builtin_amdgcn_mfma_f32_16x16x32_f16(fa[i], fb, acc[i][j], 0, 0, 0);
        }
        __builtin_amdgcn_s_waitcnt(WAIT_LGKM0);
        __builtin_amdgcn_s_barrier();
    }

    #pragma unroll
    for (int i = 0; i < 4; ++i) {
        const long gr0 = rowBase + wm * 64 + i * 16 + kq * 4;
        #pragma unroll
        for (int j = 0; j < 4; ++j) {
            const long gc = colBase + wn * 64 + j * 16 + l16;
            f32x4 a = acc[i][j];
            if constexpr (EPI == 2) {
                const int b  = (int)(gr0 / 2304);
                const int n0 = (int)(gr0 - (long)b * 2304);
                u16x4 o4;
                #pragma unroll
                for (int r = 0; r < 4; ++r) o4[r] = __builtin_bit_cast(u16, (f16)a[r]);
                *(u16x4*)&Ch[(long)b * (1024L * 2304) + gc * 2304 + n0] = o4;
            } else {
                float* C = Cf + (long)z * strC;
                const float bv = bias[gc];
                #pragma unroll
                for (int r = 0; r < 4; ++r) C[(gr0 + r) * (long)N + gc] = a[r] + bv;
            }
        }
    }
}

// ---------------------------------------------------------------------------
// Row softmax over 2304 cols with per-column bias c[m]; fp32 in, fp16 out.
// ---------------------------------------------------------------------------
__global__ __launch_bounds__(256) void softmax_k(const float* __restrict__ adj,
                                                 const float* __restrict__ c,
                                                 u16* __restrict__ P) {
    const int n = 2304;
    const int row = blockIdx.x, b = blockIdx.y;
    const int tid = threadIdx.x;
    const float* ar = adj + ((long)b * n + row) * (long)n;
    const float* cb = c + (long)b * n;
    u16* pr = P + ((long)b * n + row) * (long)n;

    float v[9];
    float mx = -3.0e38f;
    #pragma unroll
    for (int t = 0; t < 9; ++t) {
        const int i = t * 256 + tid;
        const float x = ar[i] + cb[i];
        v[t] = x;
        mx = fmaxf(mx, x);
    }
    #pragma unroll
    for (int off = 32; off >= 1; off >>= 1) mx = fmaxf(mx, __shfl_down(mx, off));
    __shared__ float red[4];
    if ((tid & 63) == 0) red[tid >> 6] = mx;
    __syncthreads();
    mx = fmaxf(fmaxf(red[0], red[1]), fmaxf(red[2], red[3]));

    float s = 0.f;
    #pragma unroll
    for (int t = 0; t < 9; ++t) {
        const float e = __expf(v[t] - mx);
        v[t] = e;
        s += e;
    }
    #pragma unroll
    for (int off = 32; off >= 1; off >>= 1) s += __shfl_down(s, off);
    __shared__ float red2[4];
    if ((tid & 63) == 0) red2[tid >> 6] = s;
    __syncthreads();
    s = red2[0] + red2[1] + red2[2] + red2[3];
    const float inv = 1.0f / s;
    #pragma unroll
    for (int t = 0; t < 9; ++t)
        pr[t * 256 + tid] = __builtin_bit_cast(u16, (f16)(v[t] * inv));
}

// ---------------------------------------------------------------------------
// Host launch
// ---------------------------------------------------------------------------
extern "C" void kernel_launch(void* const* d_in, const int* in_sizes, int n_in,
                              void* d_out, int out_size, void* d_ws, size_t ws_size,
                              hipStream_t stream) {
    (void)in_sizes; (void)n_in; (void)out_size; (void)ws_size;
    const float* F  = (const float*)d_in[0];
    const float* Wq = (const float*)d_in[1];
    const float* bq = (const float*)d_in[2];
    const float* Wk = (const float*)d_in[3];
    const float* Wu = (const float*)d_in[5];
    const float* bu = (const float*)d_in[6];
    float* out = (float*)d_out;

    char* ws = (char*)d_ws;
    const long o_F16  = 0L;
    const long o_Fh8  = 37748736L;
    const long o_Fl8  = 56623104L;
    const long o_Sh8  = 75497472L;
    const long o_Sl8  = 94371840L;
    const long o_adj  = 113246208L;              // 84,934,656 B
    const long o_P    = 198180864L;
    const long o_vT   = 240648192L;
    const long o_WuT  = 259522560L;
    const long o_Wqh  = 263716864L;
    const long o_Wql  = 267911168L;
    const long o_Wkh  = 272105472L;
    const long o_Wkl  = 276299776L;
    const long o_Mth  = 280494080L;
    const long o_Mtl  = 284688384L;
    const long o_u    = 288882688L;
    const long o_c    = 288890880L;

    u16* F16 = (u16*)(ws + o_F16);
    i8*  Fh8 = (i8*)(ws + o_Fh8);   i8* Fl8 = (i8*)(ws + o_Fl8);
    i8*  Sh8 = (i8*)(ws + o_Sh8);   i8* Sl8 = (i8*)(ws + o_Sl8);
    float* adj = (float*)(ws + o_adj);
    u16* P   = (u16*)(ws + o_P);
    u16* vT  = (u16*)(ws + o_vT);
    u16* WuT = (u16*)(ws + o_WuT);
    i8*  Wqh = (i8*)(ws + o_Wqh);   i8* Wql = (i8*)(ws + o_Wql);
    i8*  Wkh = (i8*)(ws + o_Wkh);   i8* Wkl = (i8*)(ws + o_Wkl);
    i8*  Mth = (i8*)(ws + o_Mth);   i8* Mtl = (i8*)(ws + o_Mtl);
    float* u = (float*)(ws + o_u);
    float* c = (float*)(ws + o_c);

    // stream-K partial slots for Mt/S: alias the (dead-at-that-point) adj
    // buffer: head = 512*64KB, tail = 512*64KB -> 67.1 MB <= 84.9 MB.
    float* phead = (float*)(ws + o_adj);
    float* ptail = (float*)(ws + o_adj + 33554432L);

    // --- pre-passes ---
    gemv_k<<<2048, 256, 0, stream>>>(Wk, bq, u, 2048);
    quantFc_k<<<9216, 256, 0, stream>>>(F, u, F16, Fh8, Fl8, c);
    quantW_k<<<16384, 256, 0, stream>>>(Wq, Wqh, Wql, 4194304L);
    quantW_k<<<16384, 256, 0, stream>>>(Wk, Wkh, Wkl, 4194304L);
    wut_k<<<dim3(32, 64, 1), dim3(32, 8, 1), 0, stream>>>(Wu, WuT);

    // --- Mt = Wk @ Wq^T [2048x2048]: tiles 16x16, nk=32, upb=16 ---
    gemm_i8_sk<0><<<512, 256, 0, stream>>>(
        Wkh, Wkl, Wqh, Wql, Mth, Mtl, nullptr, phead, ptail,
        3.8296569e-06f, 2048, 2048, 0L, 0L, 0L, 16, 16, 32, 16);
    fixup_k<<<256, 256, 0, stream>>>(phead, ptail, Mth, Mtl,
        3.8296569e-06f, 16, 16, 32, 16, 2048);

    // --- S = F @ Mt^T [9216x2048]: tiles 72x16, nk=32, upb=72 ---
    gemm_i8_sk<0><<<512, 256, 0, stream>>>(
        Fh8, Fl8, Mth, Mtl, Sh8, Sl8, nullptr, phead, ptail,
        3.8296569e-06f, 2048, 2048, 0L, 0L, 0L, 72, 16, 32, 72);
    fixup_k<<<1152, 256, 0, stream>>>(phead, ptail, Sh8, Sl8,
        3.8296569e-06f, 72, 16, 32, 72, 2048);

    // --- adj = S @ F^T per batch [2304x2304]: tiles 18x18x4, nk=32, upb=81 ---
    zero_split_k<<<1296, 256, 0, stream>>>(adj, 18, 18, 32, 81, 2304, 2304L * 2304);
    gemm_i8_sk<1><<<512, 256, 0, stream>>>(
        Sh8, Sl8, Fh8, Fl8, nullptr, nullptr, adj, nullptr, nullptr,
        3.3791083e-08f, 2304, 2048,
        2304L * 2048, 2304L * 2048, 2304L * 2304, 18, 18, 32, 81);

    // --- P = softmax(adj + c), fp16 ---
    softmax_k<<<dim3(2304, 4, 1), 256, 0, stream>>>(adj, c, P);

    // --- v = F @ Wu (fp16), transposed write vT[b][1024][2304] ---
    gemm_f16<2><<<dim3(8, 72, 1), 256, 0, stream>>>(
        F16, WuT, vT, nullptr, nullptr, 1024, 2048, 0L, 0L, 0L);

    // --- out = P @ v + bu, fp32 ---
    gemm_f16<3><<<dim3(8, 18, 4), 256, 0, stream>>>(
        P, vT, nullptr, out, bu, 1024, 2304,
        2304L * 2304, 1024L * 2304, 2304L * 1024);
}